// Round 1
// baseline (164.673 us; speedup 1.0000x reference)
//
#include <hip/hip_runtime.h>
#include <hip/hip_bf16.h>

typedef __hip_bfloat16 bf16;
typedef __attribute__((ext_vector_type(8))) short bf16x8;  // MFMA A/B frag (4 VGPR)
typedef __attribute__((ext_vector_type(4))) float f32x4;   // MFMA C/D frag

#define B_    2
#define C_    256
#define O_    256
#define H_    96
#define W_    96
#define HW_   9216
#define K_    9
#define PADP  8
#define XP_   112            // 96 + 2*8 halo
#define XPXP_ 12544          // 112*112
#define NS_   36             // K-slices: 2304/64
#define XT_ELEMS   (B_*XPXP_*C_)   // 6,422,528 bf16
#define BMAT_ELEMS (NS_*16384)     // 589,824 bf16

// ---------- prep 1: x (B,C,H,W) f32 -> xT[b][y+8][x+8][c] bf16, halo pre-zeroed ----------
__global__ __launch_bounds__(256) void k_prep_x(const float* __restrict__ x, bf16* __restrict__ xT) {
    __shared__ float tile[64 * 97];            // 97-stride: conflict-free on both phases
    int blk = blockIdx.x;                      // ((b*96)+y)*4 + cg
    int cg  = blk & 3;
    int y   = (blk >> 2) % 96;
    int b   = blk / 384;
    int t   = threadIdx.x;
    const float* src = x + (((size_t)(b*256 + cg*64))*96 + y)*96;
    for (int e = t; e < 6144; e += 256) {      // read coalesced along W
        int c = e / 96, wcol = e - c*96;
        tile[c*97 + wcol] = src[(size_t)c*HW_ + wcol];
    }
    __syncthreads();
    bf16* dst = xT + ((size_t)b*XPXP_ + (size_t)(y+PADP)*XP_ + PADP)*256 + cg*64;
    for (int e = t; e < 6144; e += 256) {      // write coalesced along C
        int wcol = e >> 6, c = e & 63;
        dst[(size_t)wcol*256 + c] = __float2bfloat16(tile[c*97 + wcol]);
    }
}

// ---------- prep 2: weight (O,C,3,3) f32 -> bf16 blocked [slice][o][j], pre-XOR-swizzled ----------
// slice s: kernel-pos k = s>>2, channels c = (s&3)*64 + j. LDS image row o stride 128B,
// swizzle u16idx ^= (o&7)<<3  (T2 bank-conflict fix applied at pack time).
__global__ __launch_bounds__(256) void k_prep_w(const float* __restrict__ wgt, bf16* __restrict__ bmat) {
    int id = blockIdx.x*256 + threadIdx.x;     // < 589824
    int s = id >> 14, r = id & 16383;
    int o = r >> 6,  j = r & 63;
    int c = ((s & 3) << 6) + j;
    int k = s >> 2;
    float v = wgt[((size_t)o*256 + c)*9 + k];
    int swz = ((o << 6) + j) ^ ((o & 7) << 3);
    bmat[(s << 14) + swz] = __float2bfloat16(v);
}

// ---------- main: fused deformable-sample + implicit GEMM ----------
// block = one (b,h) image row: BM=96 (m = w), BN=256 (all o), BK=64. 8 waves, wave tile 48x64.
__global__ __launch_bounds__(512, 2) void k_main(
        const bf16* __restrict__ xT, const bf16* __restrict__ bmat,
        const float* __restrict__ offs, const float* __restrict__ maskp,
        const float* __restrict__ bias, float* __restrict__ out)
{
    __shared__ __align__(16) bf16 As[96*64];    // 12 KB, swizzled
    __shared__ __align__(16) bf16 Bs[256*64];   // 32 KB, swizzled (pre-swizzled global)
    __shared__ int    geo_i[96];
    __shared__ float4 geo_w[96];

    int blk0 = blockIdx.x;                      // 0..191
    int blk  = (blk0 & 7)*24 + (blk0 >> 3);     // bijective XCD-chunked swizzle (192%8==0)
    int b = blk / 96;
    int h = blk % 96;

    int tid  = threadIdx.x;
    int lane = tid & 63;
    int wid  = tid >> 6;
    int wm = wid >> 2, wn = wid & 3;            // 2x4 wave grid

    f32x4 acc[3][4];
    #pragma unroll
    for (int i = 0; i < 3; ++i)
        #pragma unroll
        for (int jj = 0; jj < 4; ++jj) acc[i][jj] = (f32x4){0.f,0.f,0.f,0.f};

    const bf16* xb = xT + (size_t)b*XPXP_*256;

    for (int s = 0; s < NS_; ++s) {
        int k  = s >> 2;
        int c0 = (s & 3) << 6;
        // stage B slice (32 KB contiguous, pre-swizzled) into regs early
        const uint4* bsrc = (const uint4*)(bmat + (s << 14));
        uint4 br0 = bsrc[tid], br1 = bsrc[tid+512], br2 = bsrc[tid+1024], br3 = bsrc[tid+1536];

        if ((s & 3) == 0 && tid < 96) {         // per-row geometry for kernel-pos k
            int w = tid;
            float offy = offs[(((size_t)b*18 + 2*k    )*96 + h)*96 + w];
            float offx = offs[(((size_t)b*18 + 2*k + 1)*96 + h)*96 + w];
            float mv   = maskp[(((size_t)b*9 + k)*96 + h)*96 + w];
            int ky = k/3 - 1, kx = k - (k/3)*3 - 1;
            float py = (float)(h + ky) + offy;
            float px = (float)(w + kx) + offx;
            py = fminf(fmaxf(py, -7.5f), 102.4f);   // safety clamp into halo (never active for N(0,1) offsets)
            px = fminf(fmaxf(px, -7.5f), 102.4f);
            float y0 = floorf(py), x0 = floorf(px);
            float dy = py - y0,   dx = px - x0;
            geo_i[w] = ((int)y0 + PADP)*(XP_*256) + ((int)x0 + PADP)*256;
            geo_w[w] = make_float4((1.f-dy)*(1.f-dx)*mv, (1.f-dy)*dx*mv,
                                   dy*(1.f-dx)*mv,       dy*dx*mv);
        }
        __syncthreads();                        // (a) prev MFMA readers done + geo visible

        // A-fill: lane = channel (coalesced 128B per tap), 12 rows per wave
        {
            const bf16* xc = xb + c0 + lane;
            #pragma unroll 4
            for (int r = 0; r < 12; ++r) {
                int row = wid*12 + r;
                int i00 = geo_i[row];           // broadcast LDS reads
                float4 wt = geo_w[row];
                float v = wt.x*__bfloat162float(xc[i00])
                        + wt.y*__bfloat162float(xc[i00+256])
                        + wt.z*__bfloat162float(xc[i00+XP_*256])
                        + wt.w*__bfloat162float(xc[i00+XP_*256+256]);
                int widx = ((row << 6) + lane) ^ ((row & 7) << 3);  // T2 swizzle
                As[widx] = __float2bfloat16(v);
            }
        }
        // B LDS write (linear copy of pre-swizzled data)
        {
            uint4* bdst = (uint4*)Bs;
            bdst[tid] = br0; bdst[tid+512] = br1; bdst[tid+1024] = br2; bdst[tid+1536] = br3;
        }
        __syncthreads();                        // (b) tiles ready

        #pragma unroll
        for (int kh = 0; kh < 2; ++kh) {
            int kb = (kh << 6) + ((lane >> 4) << 4);   // byte offset of lane's 8-elem k-chunk
            bf16x8 a[3], bb[4];
            #pragma unroll
            for (int fm = 0; fm < 3; ++fm) {
                int row = wm*48 + fm*16 + (lane & 15);
                int byteA = ((row << 7) + kb) ^ ((row & 7) << 4);
                a[fm] = *(const bf16x8*)((const char*)As + byteA);
            }
            #pragma unroll
            for (int fn = 0; fn < 4; ++fn) {
                int o = wn*64 + fn*16 + (lane & 15);
                int byteB = ((o << 7) + kb) ^ ((o & 7) << 4);
                bb[fn] = *(const bf16x8*)((const char*)Bs + byteB);
            }
            #pragma unroll
            for (int fm = 0; fm < 3; ++fm)
                #pragma unroll
                for (int fn = 0; fn < 4; ++fn)
                    acc[fm][fn] = __builtin_amdgcn_mfma_f32_16x16x32_bf16(a[fm], bb[fn], acc[fm][fn], 0, 0, 0);
        }
    }

    // epilogue: C/D frag col=lane&15 (o), row=(lane>>4)*4+j (w). 4 consecutive w -> float4 store.
    #pragma unroll
    for (int fn = 0; fn < 4; ++fn) {
        int o = wn*64 + fn*16 + (lane & 15);
        float bv = bias[o];
        #pragma unroll
        for (int fm = 0; fm < 3; ++fm) {
            int wpos = wm*48 + fm*16 + ((lane >> 4) << 2);
            float4 vo;
            vo.x = acc[fm][fn][0] + bv;
            vo.y = acc[fm][fn][1] + bv;
            vo.z = acc[fm][fn][2] + bv;
            vo.w = acc[fm][fn][3] + bv;
            *(float4*)(out + ((size_t)(b*256 + o)*96 + h)*96 + wpos) = vo;
        }
    }
}

// ---------- GroupNorm stats: one block per (b,g), exact tree reduction ----------
__global__ __launch_bounds__(256) void k_stats(const float* __restrict__ out, float* __restrict__ stats) {
    int bg = blockIdx.x;                               // b*16+g; region is contiguous
    const float4* src = (const float4*)(out + (size_t)bg*16*HW_);
    float s1 = 0.f, s2 = 0.f;
    for (int i = threadIdx.x; i < 36864; i += 256) {
        float4 v = src[i];
        s1 += v.x+v.y+v.z+v.w;
        s2 += v.x*v.x+v.y*v.y+v.z*v.z+v.w*v.w;
    }
    __shared__ float a1[256], a2[256];
    a1[threadIdx.x] = s1; a2[threadIdx.x] = s2;
    __syncthreads();
    for (int off = 128; off > 0; off >>= 1) {
        if (threadIdx.x < off) { a1[threadIdx.x] += a1[threadIdx.x+off]; a2[threadIdx.x] += a2[threadIdx.x+off]; }
        __syncthreads();
    }
    if (threadIdx.x == 0) {
        float inv_n = 1.f/147456.f;
        float mean = a1[0]*inv_n;
        float var  = fmaxf(a2[0]*inv_n - mean*mean, 0.f);
        stats[bg*2]   = mean;
        stats[bg*2+1] = rsqrtf(var + 1e-5f);
    }
}

// ---------- normalize in place ----------
__global__ __launch_bounds__(256) void k_norm(float* __restrict__ out, const float* __restrict__ stats,
                                              const float* __restrict__ gamma, const float* __restrict__ beta) {
    int i4 = blockIdx.x*256 + threadIdx.x;             // < 1179648
    int p  = i4 / 2304;                                // = b*256+o
    int o  = p & 255;
    float mean = stats[(p>>4)*2], rstd = stats[(p>>4)*2 + 1];
    float ga = gamma[o], be = beta[o];
    float4 v = ((const float4*)out)[i4];
    v.x = (v.x-mean)*rstd*ga + be;
    v.y = (v.y-mean)*rstd*ga + be;
    v.z = (v.z-mean)*rstd*ga + be;
    v.w = (v.w-mean)*rstd*ga + be;
    ((float4*)out)[i4] = v;
}

extern "C" void kernel_launch(void* const* d_in, const int* in_sizes, int n_in,
                              void* d_out, int out_size, void* d_ws, size_t ws_size,
                              hipStream_t stream) {
    const float* x      = (const float*)d_in[0];
    const float* offset = (const float*)d_in[1];
    const float* mask   = (const float*)d_in[2];
    const float* weight = (const float*)d_in[3];
    const float* bias   = (const float*)d_in[4];
    const float* gamma  = (const float*)d_in[5];
    const float* beta   = (const float*)d_in[6];
    float* out = (float*)d_out;

    bf16* xT    = (bf16*)d_ws;
    bf16* bmat  = xT + XT_ELEMS;
    float* stats = (float*)(bmat + BMAT_ELEMS);        // 16B-aligned (both offsets %16==0)

    hipMemsetAsync(xT, 0, (size_t)XT_ELEMS*sizeof(bf16), stream);  // zero halo
    k_prep_x<<<768, 256, 0, stream>>>(x, xT);
    k_prep_w<<<2304, 256, 0, stream>>>(weight, bmat);
    k_main<<<192, 512, 0, stream>>>(xT, bmat, offset, mask, bias, out);
    k_stats<<<32, 256, 0, stream>>>(out, stats);
    k_norm<<<4608, 256, 0, stream>>>(out, stats, gamma, beta);
}

// Round 3
// 108.511 us; speedup vs baseline: 1.5176x; 1.5176x over previous
//
#include <hip/hip_runtime.h>
#include <hip/hip_bf16.h>

typedef __hip_bfloat16 bf16;
typedef __attribute__((ext_vector_type(8))) short bf16x8;  // MFMA A/B frag (4 VGPR)
typedef __attribute__((ext_vector_type(4))) float f32x4;   // MFMA C/D frag

#define B_    2
#define C_    256
#define O_    256
#define H_    96
#define W_    96
#define HW_   9216
#define PADP  8
#define XP_   112            // 96 + 2*8 halo
#define XPXP_ 12544          // 112*112
#define XP2_  28672          // XP_*256 (one padded image row, in elements)
#define NS_   36             // K-slices: 2304/64
#define NBLK  576            // 2b * 96h * 3 w-thirds
#define XT_ELEMS   (B_*XPXP_*C_)   // 6,422,528 bf16
#define BMAT_ELEMS (NS_*16384)     // 589,824 bf16

#define GLOAD_LDS16(g, l) \
  __builtin_amdgcn_global_load_lds((const __attribute__((address_space(1))) void*)(g), \
                                   (__attribute__((address_space(3))) void*)(l), 16, 0, 0)

__device__ __forceinline__ float b2f(unsigned short u) {
    return __uint_as_float(((unsigned)u) << 16);
}
__device__ __forceinline__ unsigned short f2b(float f) {
    bf16 t = __float2bfloat16(f);
    union { bf16 b; unsigned short u; } cv;
    cv.b = t;
    return cv.u;
}

// ---------- prep 1: x (B,C,H,W) f32 -> xT[b][y+8][x+8][c] bf16, halo pre-zeroed ----------
__global__ __launch_bounds__(256) void k_prep_x(const float* __restrict__ x, bf16* __restrict__ xT) {
    __shared__ float tile[64 * 97];
    int blk = blockIdx.x;                      // ((b*96)+y)*4 + cg
    int cg  = blk & 3;
    int y   = (blk >> 2) % 96;
    int b   = blk / 384;
    int t   = threadIdx.x;
    const float* src = x + (((size_t)(b*256 + cg*64))*96 + y)*96;
    for (int e = t; e < 6144; e += 256) {
        int c = e / 96, wcol = e - c*96;
        tile[c*97 + wcol] = src[(size_t)c*HW_ + wcol];
    }
    __syncthreads();
    bf16* dst = xT + ((size_t)b*XPXP_ + (size_t)(y+PADP)*XP_ + PADP)*256 + cg*64;
    for (int e = t; e < 6144; e += 256) {
        int wcol = e >> 6, c = e & 63;
        dst[(size_t)wcol*256 + c] = __float2bfloat16(tile[c*97 + wcol]);
    }
}

// ---------- prep 2: weight (O,C,3,3) f32 -> bf16 blocked [slice][o][j], pre-XOR-swizzled ----------
__global__ __launch_bounds__(256) void k_prep_w(const float* __restrict__ wgt, bf16* __restrict__ bmat) {
    int id = blockIdx.x*256 + threadIdx.x;     // < 589824
    int s = id >> 14, r = id & 16383;
    int o = r >> 6,  j = r & 63;
    int c = ((s & 3) << 6) + j;
    int k = s >> 2;
    float v = wgt[((size_t)o*256 + c)*9 + k];
    int swz = ((o << 6) + j) ^ ((o & 7) << 3);
    bmat[(s << 14) + swz] = __float2bfloat16(v);
}

// ---------- main: fused deformable-sample + implicit GEMM ----------
// block = 32 consecutive w of one (b,h) row: BM=32, BN=256, BK=64. 4 waves (2x2),
// wave tile 16x128. grid=576 -> all blocks co-resident at 4 blocks/CU.
__global__ __launch_bounds__(256, 4) void k_main(
        const bf16* __restrict__ xT, const bf16* __restrict__ bmat,
        const float* __restrict__ offs, const float* __restrict__ maskp,
        const float* __restrict__ bias, float* __restrict__ out,
        float* __restrict__ part)
{
    __shared__ __align__(16) bf16 As[32*64];    // 4KB, swizzled
    __shared__ __align__(16) bf16 Bs[256*64];   // 32KB, swizzled (pre-swizzled global, linear dest)
    __shared__ int    geo_i[32];
    __shared__ float4 geo_w[32];
    __shared__ float  psum[4][8][2];

    int blk0 = blockIdx.x;                      // 0..575
    int blk  = (blk0 & 7)*72 + (blk0 >> 3);     // bijective XCD-chunked swizzle (576%8==0)
    int b   = blk / 288;
    int rem = blk % 288;
    int h   = rem / 3;
    int w0  = (rem % 3) << 5;

    int tid  = threadIdx.x;
    int lane = tid & 63;
    int wid  = tid >> 6;
    int wm = wid >> 1, wn = wid & 1;            // 2x2 wave grid

    f32x4 acc[8];
    #pragma unroll
    for (int i = 0; i < 8; ++i) acc[i] = (f32x4){0.f,0.f,0.f,0.f};

    const bf16* xb = xT + (size_t)b*XPXP_*256;

    for (int s = 0; s < NS_; ++s) {
        int k  = s >> 2;
        int c0 = (s & 3) << 6;

        if ((s & 3) == 0 && tid < 32) {         // geometry for kernel-pos k, 32 w-positions
            int w = w0 + tid;
            float offy = offs[(((size_t)b*18 + 2*k    )*96 + h)*96 + w];
            float offx = offs[(((size_t)b*18 + 2*k + 1)*96 + h)*96 + w];
            float mv   = maskp[(((size_t)b*9 + k)*96 + h)*96 + w];
            int ky = k/3 - 1, kx = k - (k/3)*3 - 1;
            float py = (float)(h + ky) + offy;
            float px = (float)(w + kx) + offx;
            py = fminf(fmaxf(py, -7.5f), 102.4f);   // keep taps inside zero halo
            px = fminf(fmaxf(px, -7.5f), 102.4f);
            float y0 = floorf(py), x0 = floorf(px);
            float dy = py - y0,   dx = px - x0;
            geo_i[tid] = ((int)y0 + PADP)*(XP_*256) + ((int)x0 + PADP)*256;
            geo_w[tid] = make_float4((1.f-dy)*(1.f-dx)*mv, (1.f-dy)*dx*mv,
                                     dy*(1.f-dx)*mv,       dy*dx*mv);
        }
        __syncthreads();                        // prev MFMA readers done + geo visible

        // B slice: async global->LDS, 8 chunks of 1KB per wave (linear dest, pre-swizzled src)
        {
            const char* gbase = (const char*)bmat + ((size_t)s << 15);
            #pragma unroll
            for (int i = 0; i < 8; ++i) {
                int chunk = wid*8 + i;
                GLOAD_LDS16(gbase + (chunk << 10) + (lane << 4), (char*)Bs + (chunk << 10));
            }
        }

        // A-fill: 8 rows per wave, 4 rows per instr (lane>>4), 4 channels per lane (ushort4)
        {
            const bf16* xc = xb + c0;
            #pragma unroll
            for (int it = 0; it < 2; ++it) {
                int row = wid*8 + it*4 + (lane >> 4);
                int cq  = lane & 15;
                int i00 = geo_i[row];
                float4 wt = geo_w[row];
                const bf16* p = xc + i00 + cq*4;
                ushort4 v00 = *(const ushort4*)(p);
                ushort4 v01 = *(const ushort4*)(p + 256);
                ushort4 v10 = *(const ushort4*)(p + XP2_);
                ushort4 v11 = *(const ushort4*)(p + XP2_ + 256);
                float r0 = wt.x*b2f(v00.x) + wt.y*b2f(v01.x) + wt.z*b2f(v10.x) + wt.w*b2f(v11.x);
                float r1 = wt.x*b2f(v00.y) + wt.y*b2f(v01.y) + wt.z*b2f(v10.y) + wt.w*b2f(v11.y);
                float r2 = wt.x*b2f(v00.z) + wt.y*b2f(v01.z) + wt.z*b2f(v10.z) + wt.w*b2f(v11.z);
                float r3 = wt.x*b2f(v00.w) + wt.y*b2f(v01.w) + wt.z*b2f(v10.w) + wt.w*b2f(v11.w);
                ushort4 ov;
                ov.x = f2b(r0); ov.y = f2b(r1);
                ov.z = f2b(r2); ov.w = f2b(r3);
                int byteA = ((row << 7) + (cq << 3)) ^ ((row & 7) << 4);
                *(ushort4*)((char*)As + byteA) = ov;
            }
        }
        __syncthreads();                        // drains vmcnt (B ready) + lgkm (A ready)

        #pragma unroll
        for (int kh = 0; kh < 2; ++kh) {
            int kb = (kh << 6) + ((lane >> 4) << 4);
            int arow = wm*16 + (lane & 15);
            bf16x8 a = *(const bf16x8*)((const char*)As + ((((arow << 7) + kb)) ^ ((arow & 7) << 4)));
            #pragma unroll
            for (int fn = 0; fn < 8; ++fn) {
                int o = wn*128 + fn*16 + (lane & 15);
                bf16x8 bb = *(const bf16x8*)((const char*)Bs + ((((o << 7) + kb)) ^ ((o & 7) << 4)));
                acc[fn] = __builtin_amdgcn_mfma_f32_16x16x32_bf16(a, bb, acc[fn], 0, 0, 0);
            }
        }
    }

    // ---- epilogue: bias + store + per-group partial stats (from registers) ----
    #pragma unroll
    for (int fn = 0; fn < 8; ++fn) {
        int o = wn*128 + fn*16 + (lane & 15);
        float bv = bias[o];
        acc[fn][0] += bv; acc[fn][1] += bv; acc[fn][2] += bv; acc[fn][3] += bv;
        int wl = wm*16 + ((lane >> 4) << 2);
        float4 vo;
        vo.x = acc[fn][0]; vo.y = acc[fn][1]; vo.z = acc[fn][2]; vo.w = acc[fn][3];
        *(float4*)(out + ((size_t)(b*256 + o)*96 + h)*96 + w0 + wl) = vo;
    }
    #pragma unroll
    for (int fn = 0; fn < 8; ++fn) {            // group g = wn*8+fn (o-range 16 = one group)
        float s1 = acc[fn][0] + acc[fn][1] + acc[fn][2] + acc[fn][3];
        float s2 = acc[fn][0]*acc[fn][0] + acc[fn][1]*acc[fn][1]
                 + acc[fn][2]*acc[fn][2] + acc[fn][3]*acc[fn][3];
        #pragma unroll
        for (int m = 32; m > 0; m >>= 1) {
            s1 += __shfl_xor(s1, m);
            s2 += __shfl_xor(s2, m);
        }
        if (lane == 0) { psum[wid][fn][0] = s1; psum[wid][fn][1] = s2; }
    }
    __syncthreads();
    if (tid < 16) {                             // g = tid: wn_=g>>3, fn_=g&7; waves {wn_, wn_+2}
        int wn_ = tid >> 3, fn_ = tid & 7;
        float s1 = psum[wn_][fn_][0] + psum[wn_+2][fn_][0];
        float s2 = psum[wn_][fn_][1] + psum[wn_+2][fn_][1];
        part[(size_t)blk*32 + tid*2]     = s1;
        part[(size_t)blk*32 + tid*2 + 1] = s2;
    }
}

// ---------- finalize GN stats: 32 blocks, one per (b,g) ----------
__global__ __launch_bounds__(256) void k_finalize(const float* __restrict__ part, float* __restrict__ stats) {
    int bg = blockIdx.x, b = bg >> 4, g = bg & 15;
    float s1 = 0.f, s2 = 0.f;
    for (int j = threadIdx.x; j < 288; j += 256) {
        const float* p = part + (size_t)(b*288 + j)*32 + g*2;
        s1 += p[0]; s2 += p[1];
    }
    __shared__ float a1[256], a2[256];
    a1[threadIdx.x] = s1; a2[threadIdx.x] = s2;
    __syncthreads();
    for (int off = 128; off > 0; off >>= 1) {
        if (threadIdx.x < off) { a1[threadIdx.x] += a1[threadIdx.x+off]; a2[threadIdx.x] += a2[threadIdx.x+off]; }
        __syncthreads();
    }
    if (threadIdx.x == 0) {
        float inv_n = 1.f/147456.f;
        float mean = a1[0]*inv_n;
        float var  = fmaxf(a2[0]*inv_n - mean*mean, 0.f);
        stats[bg*2]   = mean;
        stats[bg*2+1] = rsqrtf(var + 1e-5f);
    }
}

// ---------- normalize in place ----------
__global__ __launch_bounds__(256) void k_norm(float* __restrict__ out, const float* __restrict__ stats,
                                              const float* __restrict__ gamma, const float* __restrict__ beta) {
    int i4 = blockIdx.x*256 + threadIdx.x;             // < 1179648 float4s
    int p  = i4 / 2304;                                // = b*256+o
    int o  = p & 255;
    float mean = stats[(p>>4)*2], rstd = stats[(p>>4)*2 + 1];
    float ga = gamma[o], be = beta[o];
    float4 v = ((const float4*)out)[i4];
    v.x = (v.x-mean)*rstd*ga + be;
    v.y = (v.y-mean)*rstd*ga + be;
    v.z = (v.z-mean)*rstd*ga + be;
    v.w = (v.w-mean)*rstd*ga + be;
    ((float4*)out)[i4] = v;
}

extern "C" void kernel_launch(void* const* d_in, const int* in_sizes, int n_in,
                              void* d_out, int out_size, void* d_ws, size_t ws_size,
                              hipStream_t stream) {
    const float* x      = (const float*)d_in[0];
    const float* offset = (const float*)d_in[1];
    const float* mask   = (const float*)d_in[2];
    const float* weight = (const float*)d_in[3];
    const float* bias   = (const float*)d_in[4];
    const float* gamma  = (const float*)d_in[5];
    const float* beta   = (const float*)d_in[6];
    float* out = (float*)d_out;

    bf16* xT    = (bf16*)d_ws;
    bf16* bmat  = xT + XT_ELEMS;
    float* part  = (float*)(bmat + BMAT_ELEMS);        // NBLK*32 floats
    float* stats = part + NBLK*32;                     // 64 floats

    (void)hipMemsetAsync(xT, 0, (size_t)XT_ELEMS*sizeof(bf16), stream);  // zero halo
    k_prep_x<<<768, 256, 0, stream>>>(x, xT);
    k_prep_w<<<2304, 256, 0, stream>>>(weight, bmat);
    k_main<<<NBLK, 256, 0, stream>>>(xT, bmat, offset, mask, bias, out, part);
    k_finalize<<<32, 256, 0, stream>>>(part, stats);
    k_norm<<<4608, 256, 0, stream>>>(out, stats, gamma, beta);
}

// Round 4
// 99.284 us; speedup vs baseline: 1.6586x; 1.0929x over previous
//
#include <hip/hip_runtime.h>
#include <hip/hip_bf16.h>

typedef __hip_bfloat16 bf16;
typedef __attribute__((ext_vector_type(8))) short bf16x8;  // MFMA A/B frag (4 VGPR)
typedef __attribute__((ext_vector_type(4))) float f32x4;   // MFMA C/D frag

#define B_    2
#define C_    256
#define O_    256
#define H_    96
#define W_    96
#define HW_   9216
#define PADP  8
#define XP_   112            // 96 + 2*8 halo
#define XPXP_ 12544          // 112*112
#define XP2_  28672          // XP_*256 (one padded image row, in elements)
#define NS_   36             // K-slices: 2304/64
#define NBLK  768            // 2b * 96h * 2wh * 2oh  -> exactly 3 blocks/CU
#define XT_ELEMS   (B_*XPXP_*C_)   // 6,422,528 bf16
#define BMAT_ELEMS (NS_*16384)     // 589,824 bf16

#define GLOAD_LDS16(g, l) \
  __builtin_amdgcn_global_load_lds((const __attribute__((address_space(1))) void*)(g), \
                                   (__attribute__((address_space(3))) void*)(l), 16, 0, 0)

__device__ __forceinline__ float b2f(unsigned short u) {
    return __uint_as_float(((unsigned)u) << 16);
}
__device__ __forceinline__ unsigned short f2b(float f) {
    bf16 t = __float2bfloat16(f);
    union { bf16 b; unsigned short u; } cv;
    cv.b = t;
    return cv.u;
}

// ---------- prep 1: x (B,C,H,W) f32 -> xT[b][y+8][x+8][c] bf16, halo pre-zeroed ----------
__global__ __launch_bounds__(256) void k_prep_x(const float* __restrict__ x, bf16* __restrict__ xT) {
    __shared__ float tile[64 * 97];
    int blk = blockIdx.x;                      // ((b*96)+y)*4 + cg
    int cg  = blk & 3;
    int y   = (blk >> 2) % 96;
    int b   = blk / 384;
    int t   = threadIdx.x;
    const float* src = x + (((size_t)(b*256 + cg*64))*96 + y)*96;
    for (int e = t; e < 6144; e += 256) {
        int c = e / 96, wcol = e - c*96;
        tile[c*97 + wcol] = src[(size_t)c*HW_ + wcol];
    }
    __syncthreads();
    bf16* dst = xT + ((size_t)b*XPXP_ + (size_t)(y+PADP)*XP_ + PADP)*256 + cg*64;
    for (int e = t; e < 6144; e += 256) {
        int wcol = e >> 6, c = e & 63;
        dst[(size_t)wcol*256 + c] = __float2bfloat16(tile[c*97 + wcol]);
    }
}

// ---------- prep 2: weight (O,C,3,3) f32 -> bf16 [slice][ohalf][o'(128)][j(64)], pre-swizzled ----------
__global__ __launch_bounds__(256) void k_prep_w(const float* __restrict__ wgt, bf16* __restrict__ bmat) {
    int id = blockIdx.x*256 + threadIdx.x;     // < 589824
    int s = id >> 14, r = id & 16383;
    int o = r >> 6,  j = r & 63;
    int c = ((s & 3) << 6) + j;
    int k = s >> 2;
    float v = wgt[((size_t)o*256 + c)*9 + k];
    int oh = o >> 7, op = o & 127;
    int swz = ((op << 6) + j) ^ ((op & 7) << 3);
    bmat[(s << 14) + (oh << 13) + swz] = __float2bfloat16(v);
}

// ---------- main: pipelined fused deformable-sample + implicit GEMM ----------
// block: BM=48 w-positions of one (b,h) row x BN=128 o's. 4 waves, wave tile 48x32.
// grid=768 -> exactly 3 blocks/CU. Double-buffered LDS, counted-wait raw barriers.
#define STEP(s_, CUR, NXT, tapC, tapN, PF) do { \
  if (PF) { \
    const char* gb = (const char*)bmat + ((size_t)((s_)+1) << 15) + (oh << 14); \
    _Pragma("unroll") \
    for (int i = 0; i < 4; ++i) \
      GLOAD_LDS16(gb + (i<<12) + (tid<<4), bsC + (NXT)*16384 + (i<<12) + (tid<<4)); \
  } \
  __builtin_amdgcn_sched_barrier(0); \
  if (PF) { \
    int kn  = ((s_)+1) >> 2; \
    int cn0 = (((s_)+1) & 3) << 6; \
    const bf16* xcn = xb + cn0 + ((lane & 15) << 2); \
    _Pragma("unroll") \
    for (int it = 0; it < 3; ++it) { \
      int row = wid*12 + it*4 + (lane >> 4); \
      int i00 = geo_i[kn*48 + row]; \
      const bf16* p = xcn + i00; \
      tapN[it*4+0] = *(const ushort4*)(p); \
      tapN[it*4+1] = *(const ushort4*)(p + 256); \
      tapN[it*4+2] = *(const ushort4*)(p + XP2_); \
      tapN[it*4+3] = *(const ushort4*)(p + XP2_ + 256); \
    } \
  } \
  { \
    int kc = (s_) >> 2; \
    _Pragma("unroll") \
    for (int it = 0; it < 3; ++it) { \
      int row = wid*12 + it*4 + (lane >> 4); \
      uint2 wp = geo_wp[kc*48 + row]; \
      float w00v = b2f((unsigned short)(wp.x & 0xffff)); \
      float w01v = b2f((unsigned short)(wp.x >> 16)); \
      float w10v = b2f((unsigned short)(wp.y & 0xffff)); \
      float w11v = b2f((unsigned short)(wp.y >> 16)); \
      ushort4 t0 = tapC[it*4+0], t1 = tapC[it*4+1], t2 = tapC[it*4+2], t3 = tapC[it*4+3]; \
      float r0 = w00v*b2f(t0.x) + w01v*b2f(t1.x) + w10v*b2f(t2.x) + w11v*b2f(t3.x); \
      float r1 = w00v*b2f(t0.y) + w01v*b2f(t1.y) + w10v*b2f(t2.y) + w11v*b2f(t3.y); \
      float r2 = w00v*b2f(t0.z) + w01v*b2f(t1.z) + w10v*b2f(t2.z) + w11v*b2f(t3.z); \
      float r3 = w00v*b2f(t0.w) + w01v*b2f(t1.w) + w10v*b2f(t2.w) + w11v*b2f(t3.w); \
      ushort4 ov; ov.x = f2b(r0); ov.y = f2b(r1); ov.z = f2b(r2); ov.w = f2b(r3); \
      int cq = lane & 15; \
      int byteA = (((row << 7) + (cq << 3)) ^ ((row & 7) << 4)) + (CUR)*6144; \
      *(ushort4*)(asC + byteA) = ov; \
    } \
  } \
  asm volatile("s_waitcnt lgkmcnt(0)" ::: "memory"); \
  __builtin_amdgcn_sched_barrier(0); \
  __builtin_amdgcn_s_barrier(); \
  __builtin_amdgcn_sched_barrier(0); \
  __builtin_amdgcn_s_setprio(1); \
  _Pragma("unroll") \
  for (int kh = 0; kh < 2; ++kh) { \
    int kb = (kh << 6) + ((lane >> 4) << 4); \
    bf16x8 av0, av1, av2, bv0, bv1; \
    { int row = (lane & 15);      av0 = *(const bf16x8*)(asC + ((((row << 7) + kb) ^ ((row & 7) << 4)) + (CUR)*6144)); } \
    { int row = 16 + (lane & 15); av1 = *(const bf16x8*)(asC + ((((row << 7) + kb) ^ ((row & 7) << 4)) + (CUR)*6144)); } \
    { int row = 32 + (lane & 15); av2 = *(const bf16x8*)(asC + ((((row << 7) + kb) ^ ((row & 7) << 4)) + (CUR)*6144)); } \
    { int op = wid*32 + (lane & 15);      bv0 = *(const bf16x8*)(bsC + ((((op << 7) + kb) ^ ((op & 7) << 4)) + (CUR)*16384)); } \
    { int op = wid*32 + 16 + (lane & 15); bv1 = *(const bf16x8*)(bsC + ((((op << 7) + kb) ^ ((op & 7) << 4)) + (CUR)*16384)); } \
    acc00 = __builtin_amdgcn_mfma_f32_16x16x32_bf16(av0, bv0, acc00, 0, 0, 0); \
    acc01 = __builtin_amdgcn_mfma_f32_16x16x32_bf16(av0, bv1, acc01, 0, 0, 0); \
    acc10 = __builtin_amdgcn_mfma_f32_16x16x32_bf16(av1, bv0, acc10, 0, 0, 0); \
    acc11 = __builtin_amdgcn_mfma_f32_16x16x32_bf16(av1, bv1, acc11, 0, 0, 0); \
    acc20 = __builtin_amdgcn_mfma_f32_16x16x32_bf16(av2, bv0, acc20, 0, 0, 0); \
    acc21 = __builtin_amdgcn_mfma_f32_16x16x32_bf16(av2, bv1, acc21, 0, 0, 0); \
  } \
  __builtin_amdgcn_s_setprio(0); \
  __builtin_amdgcn_sched_barrier(0); \
  __builtin_amdgcn_s_barrier(); \
  __builtin_amdgcn_sched_barrier(0); \
} while (0)

__global__ __launch_bounds__(256, 3) void k_main(
        const bf16* __restrict__ xT, const bf16* __restrict__ bmat,
        const float* __restrict__ offs, const float* __restrict__ maskp,
        const float* __restrict__ bias, float* __restrict__ out,
        float* __restrict__ part)
{
    __shared__ __align__(16) bf16 As[2*3072];   // 12 KB, swizzled, double-buffered
    __shared__ __align__(16) bf16 Bs[2*8192];   // 32 KB, swizzled (pre-swz global, linear dest)
    __shared__ int   geo_i[432];                // 9 k * 48 rows
    __shared__ uint2 geo_wp[432];               // 4 bf16 bilinear weights (mask folded in)

    char* asC = (char*)As;
    char* bsC = (char*)Bs;

    int blk0 = blockIdx.x;                      // 0..767
    int blk  = (blk0 & 7)*96 + (blk0 >> 3);     // bijective XCD-chunked swizzle (768%8==0)
    int oh  = blk & 1;
    int wh  = (blk >> 1) & 1;
    int h   = (blk >> 2) % 96;
    int b   = blk / 384;
    int w0g = wh * 48;

    int tid  = threadIdx.x;
    int lane = tid & 63;
    int wid  = tid >> 6;

    // ---- geometry for all 9 kernel positions, once ----
    for (int e = tid; e < 432; e += 256) {
        int k = e / 48, w = w0g + (e - k*48);
        float offy = offs[(((size_t)b*18 + 2*k    )*96 + h)*96 + w];
        float offx = offs[(((size_t)b*18 + 2*k + 1)*96 + h)*96 + w];
        float mv   = maskp[(((size_t)b*9 + k)*96 + h)*96 + w];
        int ky = k/3 - 1, kx = k - (k/3)*3 - 1;
        float py = (float)(h + ky) + offy;
        float px = (float)(w + kx) + offx;
        py = fminf(fmaxf(py, -7.5f), 102.4f);   // keep taps inside zero halo
        px = fminf(fmaxf(px, -7.5f), 102.4f);
        float y0 = floorf(py), x0 = floorf(px);
        float dy = py - y0,   dx = px - x0;
        geo_i[e] = ((int)y0 + PADP)*(XP_*256) + ((int)x0 + PADP)*256;
        float w00v = (1.f-dy)*(1.f-dx)*mv, w01v = (1.f-dy)*dx*mv;
        float w10v = dy*(1.f-dx)*mv,       w11v = dy*dx*mv;
        uint2 wp;
        wp.x = (unsigned)f2b(w00v) | ((unsigned)f2b(w01v) << 16);
        wp.y = (unsigned)f2b(w10v) | ((unsigned)f2b(w11v) << 16);
        geo_wp[e] = wp;
    }
    __syncthreads();

    f32x4 acc00 = {0,0,0,0}, acc01 = {0,0,0,0};
    f32x4 acc10 = {0,0,0,0}, acc11 = {0,0,0,0};
    f32x4 acc20 = {0,0,0,0}, acc21 = {0,0,0,0};

    const bf16* xb = xT + (size_t)b*XPXP_*256;
    ushort4 tapA[12], tapB[12];

    // ---- prologue: B(0) -> Bs[0], taps(0) -> tapA ----
    {
        const char* gb = (const char*)bmat + (oh << 14);
        #pragma unroll
        for (int i = 0; i < 4; ++i)
            GLOAD_LDS16(gb + (i<<12) + (tid<<4), bsC + (i<<12) + (tid<<4));
    }
    __builtin_amdgcn_sched_barrier(0);
    {
        const bf16* xcn = xb + ((lane & 15) << 2);
        #pragma unroll
        for (int it = 0; it < 3; ++it) {
            int row = wid*12 + it*4 + (lane >> 4);
            int i00 = geo_i[row];               // k=0
            const bf16* p = xcn + i00;
            tapA[it*4+0] = *(const ushort4*)(p);
            tapA[it*4+1] = *(const ushort4*)(p + 256);
            tapA[it*4+2] = *(const ushort4*)(p + XP2_);
            tapA[it*4+3] = *(const ushort4*)(p + XP2_ + 256);
        }
    }

    for (int sp = 0; sp < 34; sp += 2) {
        STEP(sp,   0, 1, tapA, tapB, 1);
        STEP(sp+1, 1, 0, tapB, tapA, 1);
    }
    STEP(34, 0, 1, tapA, tapB, 1);
    STEP(35, 1, 0, tapB, tapA, 0);

    // ---- epilogue: bias + store + per-group partial stats ----
    float bv0 = bias[oh*128 + wid*32 + (lane & 15)];
    float bv1 = bias[oh*128 + wid*32 + 16 + (lane & 15)];
    f32x4* accs[6] = {&acc00, &acc01, &acc10, &acc11, &acc20, &acc21};
    #pragma unroll
    for (int fm = 0; fm < 3; ++fm) {
        #pragma unroll
        for (int fn = 0; fn < 2; ++fn) {
            f32x4 a = *accs[fm*2 + fn];
            float bv = fn ? bv1 : bv0;
            a[0] += bv; a[1] += bv; a[2] += bv; a[3] += bv;
            *accs[fm*2 + fn] = a;
            int o  = oh*128 + wid*32 + fn*16 + (lane & 15);
            int wl = fm*16 + ((lane >> 4) << 2);
            float4 vo; vo.x = a[0]; vo.y = a[1]; vo.z = a[2]; vo.w = a[3];
            *(float4*)(out + ((size_t)(b*256 + o)*96 + h)*96 + w0g + wl) = vo;
        }
    }
    #pragma unroll
    for (int fn = 0; fn < 2; ++fn) {            // group = 16 consecutive o = one fn frag
        f32x4 a0 = *accs[0*2+fn], a1 = *accs[1*2+fn], a2 = *accs[2*2+fn];
        float s1 = a0[0]+a0[1]+a0[2]+a0[3] + a1[0]+a1[1]+a1[2]+a1[3] + a2[0]+a2[1]+a2[2]+a2[3];
        float s2 = a0[0]*a0[0]+a0[1]*a0[1]+a0[2]*a0[2]+a0[3]*a0[3]
                 + a1[0]*a1[0]+a1[1]*a1[1]+a1[2]*a1[2]+a1[3]*a1[3]
                 + a2[0]*a2[0]+a2[1]*a2[1]+a2[2]*a2[2]+a2[3]*a2[3];
        #pragma unroll
        for (int m = 32; m > 0; m >>= 1) {
            s1 += __shfl_xor(s1, m);
            s2 += __shfl_xor(s2, m);
        }
        if (lane == 0) {
            int gl = wid*2 + fn;
            part[(size_t)blk*16 + gl*2]     = s1;
            part[(size_t)blk*16 + gl*2 + 1] = s2;
        }
    }
}

// ---------- finalize GN stats: 32 blocks, one per (b,g) ----------
__global__ __launch_bounds__(256) void k_finalize(const float* __restrict__ part, float* __restrict__ stats) {
    int bg = blockIdx.x, b = bg >> 4, g = bg & 15;
    int ohh = g >> 3, gl = g & 7;
    float s1 = 0.f, s2 = 0.f;
    for (int j = threadIdx.x; j < 192; j += 256) {
        int h = j >> 1, wh = j & 1;
        const float* p = part + (size_t)(((((b*96 + h)*2 + wh) << 1) + ohh)*16 + gl*2);
        s1 += p[0]; s2 += p[1];
    }
    __shared__ float a1[256], a2[256];
    a1[threadIdx.x] = s1; a2[threadIdx.x] = s2;
    __syncthreads();
    for (int off = 128; off > 0; off >>= 1) {
        if (threadIdx.x < off) { a1[threadIdx.x] += a1[threadIdx.x+off]; a2[threadIdx.x] += a2[threadIdx.x+off]; }
        __syncthreads();
    }
    if (threadIdx.x == 0) {
        float inv_n = 1.f/147456.f;
        float mean = a1[0]*inv_n;
        float var  = fmaxf(a2[0]*inv_n - mean*mean, 0.f);
        stats[bg*2]   = mean;
        stats[bg*2+1] = rsqrtf(var + 1e-5f);
    }
}

// ---------- normalize in place ----------
__global__ __launch_bounds__(256) void k_norm(float* __restrict__ out, const float* __restrict__ stats,
                                              const float* __restrict__ gamma, const float* __restrict__ beta) {
    int i4 = blockIdx.x*256 + threadIdx.x;             // < 1179648 float4s
    int p  = i4 / 2304;                                // = b*256+o
    int o  = p & 255;
    float mean = stats[(p>>4)*2], rstd = stats[(p>>4)*2 + 1];
    float ga = gamma[o], be = beta[o];
    float4 v = ((const float4*)out)[i4];
    v.x = (v.x-mean)*rstd*ga + be;
    v.y = (v.y-mean)*rstd*ga + be;
    v.z = (v.z-mean)*rstd*ga + be;
    v.w = (v.w-mean)*rstd*ga + be;
    ((float4*)out)[i4] = v;
}

extern "C" void kernel_launch(void* const* d_in, const int* in_sizes, int n_in,
                              void* d_out, int out_size, void* d_ws, size_t ws_size,
                              hipStream_t stream) {
    const float* x      = (const float*)d_in[0];
    const float* offset = (const float*)d_in[1];
    const float* mask   = (const float*)d_in[2];
    const float* weight = (const float*)d_in[3];
    const float* bias   = (const float*)d_in[4];
    const float* gamma  = (const float*)d_in[5];
    const float* beta   = (const float*)d_in[6];
    float* out = (float*)d_out;

    bf16* xT    = (bf16*)d_ws;
    bf16* bmat  = xT + XT_ELEMS;
    float* part  = (float*)(bmat + BMAT_ELEMS);        // NBLK*16 floats
    float* stats = part + NBLK*16;                     // 64 floats

    (void)hipMemsetAsync(xT, 0, (size_t)XT_ELEMS*sizeof(bf16), stream);  // zero halo
    k_prep_x<<<768, 256, 0, stream>>>(x, xT);
    k_prep_w<<<2304, 256, 0, stream>>>(weight, bmat);
    k_main<<<NBLK, 256, 0, stream>>>(xT, bmat, offset, mask, bias, out, part);
    k_finalize<<<32, 256, 0, stream>>>(part, stats);
    k_norm<<<4608, 256, 0, stream>>>(out, stats, gamma, beta);
}